// Round 11
// baseline (501.085 us; speedup 1.0000x reference)
//
#include <hip/hip_runtime.h>
#include <hip/hip_cooperative_groups.h>
#include <math.h>

namespace cg = cooperative_groups;

// Problem constants (from setup_inputs)
#define NN 100000            // nodes
#define NE 1600000           // real edges
#define ET (NE + NN)         // edges + self loops = 1,700,000
#define FIN 128
#define H1 4
#define C1 8
#define F1 32                // H1*C1
#define FOUT 16
#define NSLOPE 0.2f

// Radix-partition parameters (CSR build)
#define PARTW 256                          // nodes per dst-partition
#define PSHIFT 8
#define NPART ((NN + PARTW - 1) / PARTW)   // 391
#define CPAD 16                            // ints: 1 global counter per 64B line
#define SMASK 0x1FFFF                      // low 17 bits = src id

#define K1B 512                            // k_build grid (>= NPART, >= gemm tiles)
#define EB ((ET + K1B - 1) / K1B)          // edges per block chunk = 3321

typedef _Float16 half8 __attribute__((ext_vector_type(8)));
typedef float f32x4 __attribute__((ext_vector_type(4)));

__device__ inline int wave_incl_scan(int v) {
#pragma unroll
    for (int off = 1; off < 64; off <<= 1) {
        int u = __shfl_up(v, off);
        if ((threadIdx.x & 63) >= off) v += u;
    }
    return v;
}

// ---------------- Fused CSR build + gemm1 (cooperative, 512 blocks x 256 thr) ----------------
// P0 zero -> P1 per-block LDS hist (persists in LDS) + global totals -> P2
// single-wave scan of 391 totals -> P3 range-reserve + partition-scatter ->
// P4 {per-partition counting sort | MFMA gemm1 tile} (independent, no sync).
// Replaces 6 dispatches (memset,hist,pbase,part,sort,gemm1) with one.

__global__ __launch_bounds__(256) void k_build(const int* __restrict__ srcA, const int* __restrict__ dstA,
        const float* __restrict__ x, const float* __restrict__ W1,
        const float* __restrict__ a1s, const float* __restrict__ a1d,
        int* __restrict__ ptotal, int* __restrict__ gcur, int* __restrict__ pbase,
        int* __restrict__ rowstart, int* __restrict__ pairs, int* __restrict__ epack,
        _Float16* __restrict__ xw1h, float* __restrict__ as1, float* __restrict__ ad1) {
    cg::grid_group grid = cg::this_grid();
    __shared__ int h[NPART];             // P1 hist (persists to P3), P4: sort hist (first 256)
    __shared__ int cur[NPART];           // P3 cursors, P4: scan ping
    __shared__ int sc[PARTW];            // P4: scan pong
    __shared__ _Float16 w1t[F1 * FIN];   // P4-gemm: W1^T fp16, 8 KB
    __shared__ float xs[256 * F1];       // P4-gemm: D round-trip, 32 KB
    int t = threadIdx.x;
    int b = blockIdx.x;
    int e0 = b * EB, e1 = min(e0 + EB, ET);

    // ---- P0: zero partition totals ----
    {
        int idx = b * 256 + t;
        if (idx < NPART) ptotal[idx * CPAD] = 0;
    }
    grid.sync();

    // ---- P1: per-block LDS histogram + global totals ----
    for (int i = t; i < NPART; i += 256) h[i] = 0;
    __syncthreads();
    for (int e = e0 + t; e < e1; e += 256) {
        int d = (e < NE) ? dstA[e] : (e - NE);   // virtual self-loop edges
        atomicAdd(&h[d >> PSHIFT], 1);
    }
    __syncthreads();
    for (int i = t; i < NPART; i += 256)
        if (h[i]) atomicAdd(&ptotal[i * CPAD], h[i]);
    grid.sync();

    // ---- P2: scan 391 totals (block 0, wave 0: 64 lanes x 7 entries) ----
    if (b == 0 && t < 64) {
        int base = t * 7;
        int loc[7]; int s = 0;
#pragma unroll
        for (int i = 0; i < 7; i++) {
            int idx = base + i;
            int v = (idx < NPART) ? ptotal[idx * CPAD] : 0;
            loc[i] = s; s += v;
        }
        int wex = wave_incl_scan(s) - s;   // exclusive across the 64 lanes
#pragma unroll
        for (int i = 0; i < 7; i++) {
            int idx = base + i;
            if (idx < NPART) { pbase[idx] = wex + loc[i]; gcur[idx * CPAD] = wex + loc[i]; }
        }
        if (t == 0) { pbase[NPART] = ET; rowstart[NN] = ET; }
    }
    grid.sync();

    // ---- P3: range-reserve (h[] persisted from P1) + partition scatter ----
    for (int i = t; i < NPART; i += 256) {
        int c = h[i];
        cur[i] = c ? atomicAdd(&gcur[i * CPAD], c) : 0;
    }
    __syncthreads();
    for (int e = e0 + t; e < e1; e += 256) {
        int s, d;
        if (e < NE) { s = srcA[e]; d = dstA[e]; }
        else        { s = e - NE;  d = s; }
        int pos = atomicAdd(&cur[d >> PSHIFT], 1);    // LDS atomic
        pairs[pos] = ((d & (PARTW - 1)) << 17) | s;
    }
    grid.sync();

    // ---- P4a: per-partition counting sort (blocks < NPART) ----
    if (b < NPART) {
        int n0 = b << PSHIFT;
        int nn = min(PARTW, NN - n0);
        int base = pbase[b];
        int cnt = pbase[b + 1] - base;
        if (t < PARTW) h[t] = 0;
        __syncthreads();
        for (int i = t; i < cnt; i += 256)
            atomicAdd(&h[pairs[base + i] >> 17], 1);
        __syncthreads();
        if (t < PARTW) cur[t] = h[t];
        __syncthreads();
        int* pin = cur; int* pout = sc;
        for (int off = 1; off < PARTW; off <<= 1) {
            if (t < PARTW) pout[t] = pin[t] + ((t >= off) ? pin[t - off] : 0);
            __syncthreads();
            int* tmp = pin; pin = pout; pout = tmp;
        }
        int excl = 0;
        if (t < PARTW) {
            excl = pin[t] - h[t];
            if (t < nn) rowstart[n0 + t] = base + excl;
        }
        __syncthreads();
        if (t < PARTW) h[t] = excl;   // reuse as cursor
        __syncthreads();
        for (int i = t; i < cnt; i += 256) {
            int v = pairs[base + i];
            int pos = base + atomicAdd(&h[v >> 17], 1);
            epack[pos] = v;
        }
        __syncthreads();
    }

    // ---- P4b: MFMA gemm1 tile b (blocks < 391; independent of P4a) ----
    if (b * 256 < NN) {
        {
            int i0 = t * 16;
#pragma unroll
            for (int i = 0; i < 16; i++) {
                int idx = i0 + i;
                int k = idx >> 5, n = idx & 31;
                w1t[n * FIN + k] = (_Float16)W1[idx];
            }
        }
        __syncthreads();
        int w = t >> 6, l = t & 63;
        int q = l >> 4, r16 = l & 15;
        int nblk = b * 256;
        int n0 = nblk + w * 64;
        half8 bf[4][2];
#pragma unroll
        for (int kc = 0; kc < 4; kc++)
#pragma unroll
            for (int nt = 0; nt < 2; nt++)
                bf[kc][nt] = *(const half8*)&w1t[(nt * 16 + r16) * FIN + kc * 32 + q * 8];
#pragma unroll
        for (int mt = 0; mt < 4; mt++) {
            int row = n0 + mt * 16 + r16;
            int rowc = min(row, NN - 1);
            const float4* xp = (const float4*)(x + (size_t)rowc * FIN + q * 8);
            half8 af[4];
#pragma unroll
            for (int kc = 0; kc < 4; kc++) {
                float4 u = xp[kc * 8];
                float4 v = xp[kc * 8 + 1];
                half8 a;
                a[0] = (_Float16)u.x; a[1] = (_Float16)u.y; a[2] = (_Float16)u.z; a[3] = (_Float16)u.w;
                a[4] = (_Float16)v.x; a[5] = (_Float16)v.y; a[6] = (_Float16)v.z; a[7] = (_Float16)v.w;
                af[kc] = a;
            }
            f32x4 acc0 = {0.f, 0.f, 0.f, 0.f};
            f32x4 acc1 = {0.f, 0.f, 0.f, 0.f};
#pragma unroll
            for (int kc = 0; kc < 4; kc++) {
                acc0 = __builtin_amdgcn_mfma_f32_16x16x32_f16(af[kc], bf[kc][0], acc0, 0, 0, 0);
                acc1 = __builtin_amdgcn_mfma_f32_16x16x32_f16(af[kc], bf[kc][1], acc1, 0, 0, 0);
            }
#pragma unroll
            for (int r = 0; r < 4; r++) {
                xs[(w * 64 + mt * 16 + q * 4 + r) * F1 + r16] = acc0[r];
                xs[(w * 64 + mt * 16 + q * 4 + r) * F1 + 16 + r16] = acc1[r];
            }
        }
        int node = nblk + w * 64 + l;
        if (node < NN) {
            const float4* xr = (const float4*)&xs[(w * 64 + l) * F1];
            float rowv[F1];
#pragma unroll
            for (int j = 0; j < 8; j++) {
                float4 v = xr[j];
                rowv[j * 4] = v.x; rowv[j * 4 + 1] = v.y; rowv[j * 4 + 2] = v.z; rowv[j * 4 + 3] = v.w;
            }
            half8* o8 = (half8*)(xw1h + (size_t)node * F1);
#pragma unroll
            for (int c8 = 0; c8 < F1 / 8; c8++) {
                half8 o;
#pragma unroll
                for (int k = 0; k < 8; k++) o[k] = (_Float16)rowv[c8 * 8 + k];
                o8[c8] = o;
            }
            float ss[H1], dd[H1];
#pragma unroll
            for (int hh = 0; hh < H1; hh++) {
                ss[hh] = 0.f; dd[hh] = 0.f;
#pragma unroll
                for (int c = 0; c < C1; c++) {
                    ss[hh] = fmaf(rowv[hh * C1 + c], a1s[hh * C1 + c], ss[hh]);
                    dd[hh] = fmaf(rowv[hh * C1 + c], a1d[hh * C1 + c], dd[hh]);
                }
            }
            ((float4*)as1)[node] = make_float4(ss[0], ss[1], ss[2], ss[3]);
            ((float4*)ad1)[node] = make_float4(dd[0], dd[1], dd[2], dd[3]);
        }
    }
}

// ---------------- Layer 1 gather: softmax-aggregate + bias + ELU -> h1 (fp16) ----------------
// 64 lanes per node; halves process interleaved edges, unroll x4; exp in-loop.

__global__ __launch_bounds__(256) void k_gather1(const int* __restrict__ rowstart, const int* __restrict__ epack,
        const float* __restrict__ as1, const float* __restrict__ ad1,
        const _Float16* __restrict__ xw1h, const float* __restrict__ b1,
        _Float16* __restrict__ h1h) {
    int n = blockIdx.x * 4 + (threadIdx.x >> 6);
    if (n >= NN) return;
    int l = threadIdx.x & 63;
    int c = l & 31;
    int h = c >> 3;
    int half = l >> 5;
    float adh = ad1[n * H1 + h];
    int beg = rowstart[n], end = rowstart[n + 1];
    float accn = 0.f, accd = 0.f;
    int i = beg + half;
    for (; i + 6 < end; i += 8) {
        int s0 = epack[i] & SMASK, s1 = epack[i + 2] & SMASK;
        int s2 = epack[i + 4] & SMASK, s3 = epack[i + 6] & SMASK;
        float e0 = as1[s0 * H1 + h] + adh;
        float e1 = as1[s1 * H1 + h] + adh;
        float e2 = as1[s2 * H1 + h] + adh;
        float e3 = as1[s3 * H1 + h] + adh;
        float x0 = (float)xw1h[s0 * F1 + c];
        float x1 = (float)xw1h[s1 * F1 + c];
        float x2 = (float)xw1h[s2 * F1 + c];
        float x3 = (float)xw1h[s3 * F1 + c];
        e0 = (e0 > 0.f) ? e0 : NSLOPE * e0;
        e1 = (e1 > 0.f) ? e1 : NSLOPE * e1;
        e2 = (e2 > 0.f) ? e2 : NSLOPE * e2;
        e3 = (e3 > 0.f) ? e3 : NSLOPE * e3;
        float ee0 = __expf(e0), ee1 = __expf(e1), ee2 = __expf(e2), ee3 = __expf(e3);
        accd += (ee0 + ee1) + (ee2 + ee3);
        accn = fmaf(ee0, x0, fmaf(ee1, x1, fmaf(ee2, x2, fmaf(ee3, x3, accn))));
    }
    for (; i < end; i += 2) {
        int s0 = epack[i] & SMASK;
        float e0 = as1[s0 * H1 + h] + adh;
        float x0 = (float)xw1h[s0 * F1 + c];
        e0 = (e0 > 0.f) ? e0 : NSLOPE * e0;
        float ee0 = __expf(e0);
        accd += ee0;
        accn = fmaf(ee0, x0, accn);
    }
    accn += __shfl_xor(accn, 32);
    accd += __shfl_xor(accd, 32);
    float y = accn / accd + b1[c];
    y = (y > 0.f) ? y : expm1f(y);   // ELU
    if (l < 32) h1h[(size_t)n * F1 + c] = (_Float16)y;
}

// ---------------- Layer 2 node transform: h1@W2 + attention coefficients ----------------

__global__ __launch_bounds__(256) void k_node2(const _Float16* __restrict__ h1h, const float* __restrict__ W2,
        const float* __restrict__ a2s, const float* __restrict__ a2d,
        _Float16* __restrict__ xw2h, float* __restrict__ as2, float* __restrict__ ad2) {
    int n = blockIdx.x * 256 + threadIdx.x;
    if (n >= NN) return;
    float acc[FOUT];
#pragma unroll
    for (int j = 0; j < FOUT; j++) acc[j] = 0.f;
    const half8* h8 = (const half8*)(h1h + (size_t)n * F1);
#pragma unroll
    for (int i8 = 0; i8 < F1 / 8; i8++) {
        half8 hv = h8[i8];
#pragma unroll
        for (int kk = 0; kk < 8; kk++) {
            float hk = (float)hv[kk];
            int i = i8 * 8 + kk;
#pragma unroll
            for (int j = 0; j < FOUT; j++)
                acc[j] = fmaf(hk, W2[i * FOUT + j], acc[j]);   // wave-uniform -> scalar
        }
    }
    float ss = 0.f, dd = 0.f;
#pragma unroll
    for (int j = 0; j < FOUT; j++) {
        ss = fmaf(acc[j], a2s[j], ss);
        dd = fmaf(acc[j], a2d[j], dd);
    }
    half8* o8 = (half8*)(xw2h + (size_t)n * FOUT);
#pragma unroll
    for (int j8 = 0; j8 < FOUT / 8; j8++) {
        half8 o;
#pragma unroll
        for (int k = 0; k < 8; k++) o[k] = (_Float16)acc[j8 * 8 + k];
        o8[j8] = o;
    }
    as2[n] = ss;
    ad2[n] = dd;
}

// ---------------- Layer 2 gather: softmax-aggregate + bias + log_softmax ----------------
// 64 lanes per node: quarters process interleaved edges, unroll x4; exp in-loop.

__global__ __launch_bounds__(256) void k_gather2(const int* __restrict__ rowstart, const int* __restrict__ epack,
        const float* __restrict__ as2, const float* __restrict__ ad2,
        const _Float16* __restrict__ xw2h, const float* __restrict__ b2,
        float* __restrict__ out) {
    int n = blockIdx.x * 4 + (threadIdx.x >> 6);
    if (n >= NN) return;
    int l = threadIdx.x & 63;
    int c = l & 15;
    int q = l >> 4;
    float adn = ad2[n];
    int beg = rowstart[n], end = rowstart[n + 1];
    float accn = 0.f, accd = 0.f;
    int i = beg + q;
    for (; i + 12 < end; i += 16) {
        int s0 = epack[i] & SMASK, s1 = epack[i + 4] & SMASK;
        int s2 = epack[i + 8] & SMASK, s3 = epack[i + 12] & SMASK;
        float e0 = as2[s0] + adn;
        float e1 = as2[s1] + adn;
        float e2 = as2[s2] + adn;
        float e3 = as2[s3] + adn;
        float x0 = (float)xw2h[s0 * FOUT + c];
        float x1 = (float)xw2h[s1 * FOUT + c];
        float x2 = (float)xw2h[s2 * FOUT + c];
        float x3 = (float)xw2h[s3 * FOUT + c];
        e0 = (e0 > 0.f) ? e0 : NSLOPE * e0;
        e1 = (e1 > 0.f) ? e1 : NSLOPE * e1;
        e2 = (e2 > 0.f) ? e2 : NSLOPE * e2;
        e3 = (e3 > 0.f) ? e3 : NSLOPE * e3;
        float ee0 = __expf(e0), ee1 = __expf(e1), ee2 = __expf(e2), ee3 = __expf(e3);
        accd += (ee0 + ee1) + (ee2 + ee3);
        accn = fmaf(ee0, x0, fmaf(ee1, x1, fmaf(ee2, x2, fmaf(ee3, x3, accn))));
    }
    for (; i < end; i += 4) {
        int s0 = epack[i] & SMASK;
        float e0 = as2[s0] + adn;
        float x0 = (float)xw2h[s0 * FOUT + c];
        e0 = (e0 > 0.f) ? e0 : NSLOPE * e0;
        float ee0 = __expf(e0);
        accd += ee0;
        accn = fmaf(ee0, x0, accn);
    }
    accn += __shfl_xor(accn, 16);
    accn += __shfl_xor(accn, 32);
    accd += __shfl_xor(accd, 16);
    accd += __shfl_xor(accd, 32);
    float y = accn / accd + b2[c];
    float m = y;
#pragma unroll
    for (int off = 8; off > 0; off >>= 1) m = fmaxf(m, __shfl_xor(m, off));
    float ex = __expf(y - m);
    float sum = ex;
#pragma unroll
    for (int off = 8; off > 0; off >>= 1) sum += __shfl_xor(sum, off);
    if (l < 16) out[(size_t)n * FOUT + c] = y - m - logf(sum);
}

// ---------------- launch ----------------

extern "C" void kernel_launch(void* const* d_in, const int* in_sizes, int n_in,
                              void* d_out, int out_size, void* d_ws, size_t ws_size,
                              hipStream_t stream) {
    const float* x   = (const float*)d_in[0];
    const int*   ei  = (const int*)d_in[1];
    const float* W1  = (const float*)d_in[2];
    const float* a1s = (const float*)d_in[3];
    const float* a1d = (const float*)d_in[4];
    const float* b1  = (const float*)d_in[5];
    const float* W2  = (const float*)d_in[6];
    const float* a2s = (const float*)d_in[7];
    const float* a2d = (const float*)d_in[8];
    const float* b2  = (const float*)d_in[9];
    float* out = (float*)d_out;

    const int* srcA = ei;        // edge_index[0]
    const int* dstA = ei + NE;   // edge_index[1]

    char* w = (char*)d_ws;
    size_t off = 0;
    auto carve = [&](size_t bytes) -> void* {
        void* p = w + off;
        off = (off + bytes + 255) & ~(size_t)255;
        return p;
    };
    _Float16* xw1h = (_Float16*)carve((size_t)NN * F1 * 2);   // 6.4 MB
    float* as1     = (float*)carve((size_t)NN * H1 * 4);      // 1.6 MB
    float* ad1     = (float*)carve((size_t)NN * H1 * 4);      // 1.6 MB
    // pairs (6.8MB) aliases h1h+xw2h (9.6MB): pairs dies inside k_build, h1h/
    // xw2h are written only by later kernels (stream-ordered) -> safe.
    size_t h1_off  = off;
    _Float16* h1h  = (_Float16*)carve((size_t)NN * F1 * 2);   // 6.4 MB
    _Float16* xw2h = (_Float16*)carve((size_t)NN * FOUT * 2); // 3.2 MB
    float* as2     = (float*)carve((size_t)NN * 4);
    float* ad2     = (float*)carve((size_t)NN * 4);
    int* pairs     = (int*)(w + h1_off);                      // alias
    int* rowstart  = (int*)carve((size_t)(NN + 1) * 4);
    int* epack     = (int*)carve((size_t)ET * 4);             // 6.8 MB
    int* ptotal    = (int*)carve((size_t)NPART * CPAD * 4);   // 25 KB
    int* gcur      = (int*)carve((size_t)NPART * CPAD * 4);   // 25 KB
    int* pbase     = (int*)carve((size_t)(NPART + 1) * 4);
    (void)ws_size; (void)in_sizes; (void)n_in; (void)out_size;

    void* args[] = { (void*)&srcA, (void*)&dstA, (void*)&x, (void*)&W1,
                     (void*)&a1s, (void*)&a1d, (void*)&ptotal, (void*)&gcur,
                     (void*)&pbase, (void*)&rowstart, (void*)&pairs, (void*)&epack,
                     (void*)&xw1h, (void*)&as1, (void*)&ad1 };
    hipLaunchCooperativeKernel((const void*)k_build, dim3(K1B), dim3(256), args, 0, stream);

    k_gather1<<<(NN + 3) / 4, 256, 0, stream>>>(rowstart, epack, as1, ad1, xw1h, b1, h1h);
    k_node2 <<<(NN + 255) / 256, 256, 0, stream>>>(h1h, W2, a2s, a2d, xw2h, as2, ad2);
    k_gather2<<<(NN + 3) / 4, 256, 0, stream>>>(rowstart, epack, as2, ad2, xw2h, b2, out);
}

// Round 12
// 243.922 us; speedup vs baseline: 2.0543x; 2.0543x over previous
//
#include <hip/hip_runtime.h>
#include <math.h>

// Problem constants (from setup_inputs)
#define NN 100000            // nodes
#define NE 1600000           // real edges
#define ET (NE + NN)         // edges + self loops = 1,700,000
#define FIN 128
#define H1 4
#define C1 8
#define F1 32                // H1*C1
#define FOUT 16
#define NSLOPE 0.2f

// Radix-partition parameters (CSR build)
#define PARTW 256                          // nodes per dst-partition
#define PSHIFT 8
#define NPART ((NN + PARTW - 1) / PARTW)   // 391
#define CHUNK 8192                         // edges per hist/part block
#define NBLK ((ET + CHUNK - 1) / CHUNK)    // 208
#define CPAD 16                            // ints: 1 global counter per 64B line
#define SMASK 0x1FFFF                      // low 17 bits = src id

typedef _Float16 half8 __attribute__((ext_vector_type(8)));
typedef _Float16 half2_t __attribute__((ext_vector_type(2)));
typedef float f32x4 __attribute__((ext_vector_type(4)));

// ---------------- scan helpers ----------------

__device__ inline int wave_incl_scan(int v) {
#pragma unroll
    for (int off = 1; off < 64; off <<= 1) {
        int u = __shfl_up(v, off);
        if ((threadIdx.x & 63) >= off) v += u;
    }
    return v;
}

__device__ inline int block_excl_scan(int v, int* wsum, int nw) {
    int t = threadIdx.x, wid = t >> 6, lane = t & 63;
    int incl = wave_incl_scan(v);
    if (lane == 63) wsum[wid] = incl;
    __syncthreads();
    if (wid == 0) {
        int wv = (lane < nw) ? wsum[lane] : 0;
        wv = wave_incl_scan(wv);
        if (lane < nw) wsum[lane] = wv;
    }
    __syncthreads();
    return incl - v + (wid ? wsum[wid - 1] : 0);
}

// ---------------- CSR build (R10 versions) ----------------

__global__ __launch_bounds__(1024) void k_hist(const int* __restrict__ dstA, int* __restrict__ ptotal) {
    __shared__ int h[NPART];
    int t = threadIdx.x;
    for (int i = t; i < NPART; i += 1024) h[i] = 0;
    __syncthreads();
    int base = blockIdx.x * CHUNK;
#pragma unroll
    for (int k = 0; k < CHUNK / 1024; k++) {
        int e = base + k * 1024 + t;
        if (e < ET) {
            int d = (e < NE) ? dstA[e] : (e - NE);   // virtual self-loop edges
            atomicAdd(&h[d >> PSHIFT], 1);
        }
    }
    __syncthreads();
    for (int i = t; i < NPART; i += 1024)
        if (h[i]) atomicAdd(&ptotal[i * CPAD], h[i]);
}

__global__ __launch_bounds__(512) void k_pbase(const int* __restrict__ ptotal, int* __restrict__ pbase,
                                               int* __restrict__ gcur, int* __restrict__ rowstart) {
    __shared__ int wsum[8];
    int t = threadIdx.x;
    int v = (t < NPART) ? ptotal[t * CPAD] : 0;
    int excl = block_excl_scan(v, wsum, 8);
    if (t < NPART) { pbase[t] = excl; gcur[t * CPAD] = excl; }
    if (t == 0) { pbase[NPART] = ET; rowstart[NN] = ET; }
}

__global__ __launch_bounds__(1024) void k_part(const int* __restrict__ srcA, const int* __restrict__ dstA,
                                               int* __restrict__ gcur, int* __restrict__ pairs) {
    __shared__ int h[NPART];
    __shared__ int cur[NPART];
    int t = threadIdx.x;
    for (int i = t; i < NPART; i += 1024) h[i] = 0;
    __syncthreads();
    int base = blockIdx.x * CHUNK;
#pragma unroll
    for (int k = 0; k < CHUNK / 1024; k++) {
        int e = base + k * 1024 + t;
        if (e < ET) {
            int d = (e < NE) ? dstA[e] : (e - NE);
            atomicAdd(&h[d >> PSHIFT], 1);
        }
    }
    __syncthreads();
    for (int i = t; i < NPART; i += 1024) {
        int c = h[i];
        cur[i] = c ? atomicAdd(&gcur[i * CPAD], c) : 0;   // reserve contiguous range
    }
    __syncthreads();
#pragma unroll
    for (int k = 0; k < CHUNK / 1024; k++) {
        int e = base + k * 1024 + t;
        if (e < ET) {
            int s, d;
            if (e < NE) { s = srcA[e]; d = dstA[e]; }
            else        { s = e - NE;  d = s; }
            int pos = atomicAdd(&cur[d >> PSHIFT], 1);    // LDS atomic
            pairs[pos] = ((d & (PARTW - 1)) << 17) | s;   // src < 2^17, dloc < 2^8
        }
    }
}

__global__ __launch_bounds__(1024) void k_sort(const int* __restrict__ pbase, const int* __restrict__ pairs,
                                               int* __restrict__ rowstart, int* __restrict__ epack) {
    __shared__ int hist[PARTW];
    __shared__ int sa[PARTW], sb[PARTW];
    int p = blockIdx.x;
    int t = threadIdx.x;
    int n0 = p << PSHIFT;
    int nn = min(PARTW, NN - n0);
    int base = pbase[p];
    int cnt = pbase[p + 1] - base;
    if (t < PARTW) hist[t] = 0;
    __syncthreads();
    for (int i = t; i < cnt; i += 1024)
        atomicAdd(&hist[pairs[base + i] >> 17], 1);
    __syncthreads();
    if (t < PARTW) sa[t] = hist[t];
    __syncthreads();
    int* pin = sa; int* pout = sb;
    for (int off = 1; off < PARTW; off <<= 1) {
        if (t < PARTW) pout[t] = pin[t] + ((t >= off) ? pin[t - off] : 0);
        __syncthreads();
        int* tmp = pin; pin = pout; pout = tmp;
    }
    int excl = 0;
    if (t < PARTW) {
        excl = pin[t] - hist[t];
        if (t < nn) rowstart[n0 + t] = base + excl;
    }
    __syncthreads();
    if (t < PARTW) hist[t] = excl;   // reuse as cursor
    __syncthreads();
    for (int i = t; i < cnt; i += 1024) {
        int v = pairs[base + i];
        int pos = base + atomicAdd(&hist[v >> 17], 1);  // LDS atomic
        epack[pos] = v;
    }
}

// ---------------- Layer 1: x@W1 via MFMA (R10 version, verified) ----------------

__global__ __launch_bounds__(256) void k_gemm1(const float* __restrict__ x, const float* __restrict__ W1,
        const float* __restrict__ a1s, const float* __restrict__ a1d,
        _Float16* __restrict__ xw1h, float* __restrict__ as1, float* __restrict__ ad1) {
    __shared__ _Float16 w1t[F1 * FIN];   // [n][k], 8 KB
    __shared__ float xs[256 * F1];       // [node_loc][col], 32 KB
    int t = threadIdx.x;
    {
        int i0 = t * 16;
#pragma unroll
        for (int i = 0; i < 16; i++) {
            int idx = i0 + i;
            int k = idx >> 5, n = idx & 31;
            w1t[n * FIN + k] = (_Float16)W1[idx];
        }
    }
    __syncthreads();
    int w = t >> 6, l = t & 63;
    int q = l >> 4, r16 = l & 15;
    int nblk = blockIdx.x * 256;
    int n0 = nblk + w * 64;
    half8 bf[4][2];
#pragma unroll
    for (int kc = 0; kc < 4; kc++)
#pragma unroll
        for (int nt = 0; nt < 2; nt++)
            bf[kc][nt] = *(const half8*)&w1t[(nt * 16 + r16) * FIN + kc * 32 + q * 8];
#pragma unroll
    for (int mt = 0; mt < 4; mt++) {
        int row = n0 + mt * 16 + r16;
        int rowc = min(row, NN - 1);            // clamp: values discarded for OOB rows
        const float4* xp = (const float4*)(x + (size_t)rowc * FIN + q * 8);
        half8 af[4];
#pragma unroll
        for (int kc = 0; kc < 4; kc++) {
            float4 u = xp[kc * 8];
            float4 v = xp[kc * 8 + 1];
            half8 a;
            a[0] = (_Float16)u.x; a[1] = (_Float16)u.y; a[2] = (_Float16)u.z; a[3] = (_Float16)u.w;
            a[4] = (_Float16)v.x; a[5] = (_Float16)v.y; a[6] = (_Float16)v.z; a[7] = (_Float16)v.w;
            af[kc] = a;
        }
        f32x4 acc0 = {0.f, 0.f, 0.f, 0.f};
        f32x4 acc1 = {0.f, 0.f, 0.f, 0.f};
#pragma unroll
        for (int kc = 0; kc < 4; kc++) {
            acc0 = __builtin_amdgcn_mfma_f32_16x16x32_f16(af[kc], bf[kc][0], acc0, 0, 0, 0);
            acc1 = __builtin_amdgcn_mfma_f32_16x16x32_f16(af[kc], bf[kc][1], acc1, 0, 0, 0);
        }
#pragma unroll
        for (int r = 0; r < 4; r++) {
            xs[(w * 64 + mt * 16 + q * 4 + r) * F1 + r16] = acc0[r];
            xs[(w * 64 + mt * 16 + q * 4 + r) * F1 + 16 + r16] = acc1[r];
        }
    }
    int node = nblk + w * 64 + l;
    if (node < NN) {
        const float4* xr = (const float4*)&xs[(w * 64 + l) * F1];
        float rowv[F1];
#pragma unroll
        for (int j = 0; j < 8; j++) {
            float4 v = xr[j];
            rowv[j * 4] = v.x; rowv[j * 4 + 1] = v.y; rowv[j * 4 + 2] = v.z; rowv[j * 4 + 3] = v.w;
        }
        half8* o8 = (half8*)(xw1h + (size_t)node * F1);
#pragma unroll
        for (int c8 = 0; c8 < F1 / 8; c8++) {
            half8 o;
#pragma unroll
            for (int k = 0; k < 8; k++) o[k] = (_Float16)rowv[c8 * 8 + k];
            o8[c8] = o;
        }
        float ss[H1], dd[H1];
#pragma unroll
        for (int h = 0; h < H1; h++) {
            ss[h] = 0.f; dd[h] = 0.f;
#pragma unroll
            for (int c = 0; c < C1; c++) {
                ss[h] = fmaf(rowv[h * C1 + c], a1s[h * C1 + c], ss[h]);
                dd[h] = fmaf(rowv[h * C1 + c], a1d[h * C1 + c], dd[h]);
            }
        }
        ((float4*)as1)[node] = make_float4(ss[0], ss[1], ss[2], ss[3]);
        ((float4*)ad1)[node] = make_float4(dd[0], dd[1], dd[2], dd[3]);
    }
}

// ---------------- Layer 1 gather: channel-pair restructure ----------------
// 1 wave/node. 4 edge-groups x 16 lanes; lane j owns channels {2j,2j+1} via one
// half2 load; head j>>2 unique per lane -> 1 as1 read + 1 exp per lane per edge.
// 4-wide edge parallelism + unroll x2 -> 8 edges in flight, ~half the VALU of
// the single-channel layout (R10: VALUBusy 55%).

__global__ __launch_bounds__(256) void k_gather1(const int* __restrict__ rowstart, const int* __restrict__ epack,
        const float* __restrict__ as1, const float* __restrict__ ad1,
        const _Float16* __restrict__ xw1h, const float* __restrict__ b1,
        _Float16* __restrict__ h1h) {
    int n = blockIdx.x * 4 + (threadIdx.x >> 6);
    if (n >= NN) return;
    int l = threadIdx.x & 63;
    int g = l >> 4;          // edge group
    int j = l & 15;          // channel-pair id
    int h = j >> 2;          // head
    float adh = ad1[n * H1 + h];
    const half2_t* xw = (const half2_t*)xw1h;   // row = 16 half2
    int beg = rowstart[n], end = rowstart[n + 1];
    float a0 = 0.f, a1v = 0.f, ad = 0.f;
    int i = beg + g;
    for (; i + 4 < end; i += 8) {
        int s0 = epack[i] & SMASK, s1 = epack[i + 4] & SMASK;
        float e0 = as1[s0 * H1 + h] + adh;
        float e1 = as1[s1 * H1 + h] + adh;
        half2_t v0 = xw[s0 * 16 + j];
        half2_t v1 = xw[s1 * 16 + j];
        e0 = (e0 > 0.f) ? e0 : NSLOPE * e0;
        e1 = (e1 > 0.f) ? e1 : NSLOPE * e1;
        float w0 = __expf(e0), w1 = __expf(e1);
        ad += w0 + w1;
        a0  = fmaf(w0, (float)v0[0], fmaf(w1, (float)v1[0], a0));
        a1v = fmaf(w0, (float)v0[1], fmaf(w1, (float)v1[1], a1v));
    }
    for (; i < end; i += 4) {
        int s0 = epack[i] & SMASK;
        float e0 = as1[s0 * H1 + h] + adh;
        half2_t v0 = xw[s0 * 16 + j];
        e0 = (e0 > 0.f) ? e0 : NSLOPE * e0;
        float w0 = __expf(e0);
        ad += w0;
        a0  = fmaf(w0, (float)v0[0], a0);
        a1v = fmaf(w0, (float)v0[1], a1v);
    }
#pragma unroll
    for (int off = 16; off < 64; off <<= 1) {
        a0  += __shfl_xor(a0, off);
        a1v += __shfl_xor(a1v, off);
        ad  += __shfl_xor(ad, off);
    }
    float y0 = a0 / ad + b1[2 * j];
    float y1 = a1v / ad + b1[2 * j + 1];
    y0 = (y0 > 0.f) ? y0 : expm1f(y0);   // ELU
    y1 = (y1 > 0.f) ? y1 : expm1f(y1);
    if (l < 16) {
        half2_t o; o[0] = (_Float16)y0; o[1] = (_Float16)y1;
        ((half2_t*)h1h)[(size_t)n * 16 + j] = o;
    }
}

// ---------------- Layer 2 node transform: h1@W2 + attention coefficients ----------------

__global__ __launch_bounds__(256) void k_node2(const _Float16* __restrict__ h1h, const float* __restrict__ W2,
        const float* __restrict__ a2s, const float* __restrict__ a2d,
        _Float16* __restrict__ xw2h, float* __restrict__ as2, float* __restrict__ ad2) {
    int n = blockIdx.x * 256 + threadIdx.x;
    if (n >= NN) return;
    float acc[FOUT];
#pragma unroll
    for (int j = 0; j < FOUT; j++) acc[j] = 0.f;
    const half8* h8 = (const half8*)(h1h + (size_t)n * F1);
#pragma unroll
    for (int i8 = 0; i8 < F1 / 8; i8++) {
        half8 hv = h8[i8];
#pragma unroll
        for (int kk = 0; kk < 8; kk++) {
            float hk = (float)hv[kk];
            int i = i8 * 8 + kk;
#pragma unroll
            for (int j = 0; j < FOUT; j++)
                acc[j] = fmaf(hk, W2[i * FOUT + j], acc[j]);   // wave-uniform -> scalar
        }
    }
    float ss = 0.f, dd = 0.f;
#pragma unroll
    for (int j = 0; j < FOUT; j++) {
        ss = fmaf(acc[j], a2s[j], ss);
        dd = fmaf(acc[j], a2d[j], dd);
    }
    half8* o8 = (half8*)(xw2h + (size_t)n * FOUT);
#pragma unroll
    for (int j8 = 0; j8 < FOUT / 8; j8++) {
        half8 o;
#pragma unroll
        for (int k = 0; k < 8; k++) o[k] = (_Float16)acc[j8 * 8 + k];
        o8[j8] = o;
    }
    as2[n] = ss;
    ad2[n] = dd;
}

// ---------------- Layer 2 gather: channel-pair restructure + log_softmax ----------------
// 1 wave/node. 8 edge-groups x 8 lanes; lane j owns channels {2j,2j+1}; single
// head -> 1 as2 read + 1 exp per lane. Unroll x2 -> 16 edges in flight.

__global__ __launch_bounds__(256) void k_gather2(const int* __restrict__ rowstart, const int* __restrict__ epack,
        const float* __restrict__ as2, const float* __restrict__ ad2,
        const _Float16* __restrict__ xw2h, const float* __restrict__ b2,
        float* __restrict__ out) {
    int n = blockIdx.x * 4 + (threadIdx.x >> 6);
    if (n >= NN) return;
    int l = threadIdx.x & 63;
    int g = l >> 3;          // edge group
    int j = l & 7;           // channel-pair id
    float adn = ad2[n];
    const half2_t* xw = (const half2_t*)xw2h;   // row = 8 half2
    int beg = rowstart[n], end = rowstart[n + 1];
    float a0 = 0.f, a1v = 0.f, ad = 0.f;
    int i = beg + g;
    for (; i + 8 < end; i += 16) {
        int s0 = epack[i] & SMASK, s1 = epack[i + 8] & SMASK;
        float e0 = as2[s0] + adn;
        float e1 = as2[s1] + adn;
        half2_t v0 = xw[s0 * 8 + j];
        half2_t v1 = xw[s1 * 8 + j];
        e0 = (e0 > 0.f) ? e0 : NSLOPE * e0;
        e1 = (e1 > 0.f) ? e1 : NSLOPE * e1;
        float w0 = __expf(e0), w1 = __expf(e1);
        ad += w0 + w1;
        a0  = fmaf(w0, (float)v0[0], fmaf(w1, (float)v1[0], a0));
        a1v = fmaf(w0, (float)v0[1], fmaf(w1, (float)v1[1], a1v));
    }
    for (; i < end; i += 8) {
        int s0 = epack[i] & SMASK;
        float e0 = as2[s0] + adn;
        half2_t v0 = xw[s0 * 8 + j];
        e0 = (e0 > 0.f) ? e0 : NSLOPE * e0;
        float w0 = __expf(e0);
        ad += w0;
        a0  = fmaf(w0, (float)v0[0], a0);
        a1v = fmaf(w0, (float)v0[1], a1v);
    }
#pragma unroll
    for (int off = 8; off < 64; off <<= 1) {
        a0  += __shfl_xor(a0, off);
        a1v += __shfl_xor(a1v, off);
        ad  += __shfl_xor(ad, off);
    }
    float y0 = a0 / ad + b2[2 * j];
    float y1 = a1v / ad + b2[2 * j + 1];
    // log_softmax over 16 channels (8 lanes x 2 regs)
    float m = fmaxf(y0, y1);
#pragma unroll
    for (int off = 1; off < 8; off <<= 1) m = fmaxf(m, __shfl_xor(m, off));
    float s = __expf(y0 - m) + __expf(y1 - m);
#pragma unroll
    for (int off = 1; off < 8; off <<= 1) s += __shfl_xor(s, off);
    float ls = logf(s);
    if (l < 8)
        ((float2*)out)[(size_t)n * 8 + j] = make_float2(y0 - m - ls, y1 - m - ls);
}

// ---------------- launch ----------------

extern "C" void kernel_launch(void* const* d_in, const int* in_sizes, int n_in,
                              void* d_out, int out_size, void* d_ws, size_t ws_size,
                              hipStream_t stream) {
    const float* x   = (const float*)d_in[0];
    const int*   ei  = (const int*)d_in[1];
    const float* W1  = (const float*)d_in[2];
    const float* a1s = (const float*)d_in[3];
    const float* a1d = (const float*)d_in[4];
    const float* b1  = (const float*)d_in[5];
    const float* W2  = (const float*)d_in[6];
    const float* a2s = (const float*)d_in[7];
    const float* a2d = (const float*)d_in[8];
    const float* b2  = (const float*)d_in[9];
    float* out = (float*)d_out;

    const int* srcA = ei;        // edge_index[0]
    const int* dstA = ei + NE;   // edge_index[1]

    char* w = (char*)d_ws;
    size_t off = 0;
    auto carve = [&](size_t bytes) -> void* {
        void* p = w + off;
        off = (off + bytes + 255) & ~(size_t)255;
        return p;
    };
    _Float16* xw1h = (_Float16*)carve((size_t)NN * F1 * 2);   // 6.4 MB
    float* as1     = (float*)carve((size_t)NN * H1 * 4);      // 1.6 MB
    float* ad1     = (float*)carve((size_t)NN * H1 * 4);      // 1.6 MB
    // pairs (6.8MB) aliases h1h+xw2h (9.6MB): pairs dies at k_sort, h1h/xw2h
    // are written only by later kernels (stream-ordered) -> safe.
    size_t h1_off  = off;
    _Float16* h1h  = (_Float16*)carve((size_t)NN * F1 * 2);   // 6.4 MB
    _Float16* xw2h = (_Float16*)carve((size_t)NN * FOUT * 2); // 3.2 MB
    float* as2     = (float*)carve((size_t)NN * 4);
    float* ad2     = (float*)carve((size_t)NN * 4);
    int* pairs     = (int*)(w + h1_off);                      // alias
    int* rowstart  = (int*)carve((size_t)(NN + 1) * 4);
    int* epack     = (int*)carve((size_t)ET * 4);             // 6.8 MB
    int* ptotal    = (int*)carve((size_t)NPART * CPAD * 4);   // 25 KB
    int* gcur      = (int*)carve((size_t)NPART * CPAD * 4);   // 25 KB
    int* pbase     = (int*)carve((size_t)(NPART + 1) * 4);
    (void)ws_size; (void)in_sizes; (void)n_in; (void)out_size;

    hipMemsetAsync(ptotal, 0, (size_t)NPART * CPAD * 4, stream);

    k_hist  <<<NBLK, 1024, 0, stream>>>(dstA, ptotal);
    k_pbase <<<1, 512, 0, stream>>>(ptotal, pbase, gcur, rowstart);
    k_part  <<<NBLK, 1024, 0, stream>>>(srcA, dstA, gcur, pairs);
    k_sort  <<<NPART, 1024, 0, stream>>>(pbase, pairs, rowstart, epack);

    k_gemm1 <<<(NN + 255) / 256, 256, 0, stream>>>(x, W1, a1s, a1d, xw1h, as1, ad1);
    k_gather1<<<(NN + 3) / 4, 256, 0, stream>>>(rowstart, epack, as1, ad1, xw1h, b1, h1h);
    k_node2 <<<(NN + 255) / 256, 256, 0, stream>>>(h1h, W2, a2s, a2d, xw2h, as2, ad2);
    k_gather2<<<(NN + 3) / 4, 256, 0, stream>>>(rowstart, epack, as2, ad2, xw2h, b2, out);
}